// Round 1
// baseline (106.220 us; speedup 1.0000x reference)
//
#include <hip/hip_runtime.h>

#define NPTS 512      // N rows
#define INS  512      // INSIZE
#define KDIM 64       // K groups
#define DDIM 16       // D per group
#define CDIM (KDIM*DDIM)  // 1024 output cols of the linear
#define OUTC (INS + KDIM) // 576

__device__ __forceinline__ float exp2_fast(float x) {
    return __builtin_amdgcn_exp2f(x);
}

// ---------------- Kernel A: feat = (x @ W^T + b) * log2(e), stored as featT[k][i][d]
// tile: 32 rows (i) x 64 cols (c), k-step 16. grid (CDIM/64=16, NPTS/32=16), 256 thr.
__global__ __launch_bounds__(256) void gemm_kernel(
    const float* __restrict__ x,    // [512][512]
    const float* __restrict__ W,    // [1024][512]
    const float* __restrict__ bias, // [1024]
    float* __restrict__ featT)      // [64][512][16]
{
    const int tid = threadIdx.x;
    const int cbase = blockIdx.x * 64;
    const int ibase = blockIdx.y * 32;

    __shared__ float xs[16][32 + 2];   // [kk][i], pad -> 2-way max conflicts (free)
    __shared__ float wss[16][64 + 4];  // [kk][c]

    const int tx = tid & 15;   // c group: tx*4 .. +3
    const int ty = tid >> 4;   // i group: ty*2 .. +1

    float acc[2][4] = {};

    const int kkL = tid & 15;
    const int rL  = tid >> 4;  // 0..15

    for (int k0 = 0; k0 < INS; k0 += 16) {
        // stage x tile (16kk x 32i), transposed, 2 elems/thread
        xs[kkL][rL]      = x[(ibase + rL) * INS + k0 + kkL];
        xs[kkL][rL + 16] = x[(ibase + rL + 16) * INS + k0 + kkL];
        // stage W tile (16kk x 64c), transposed, 4 elems/thread
        wss[kkL][rL]      = W[(cbase + rL) * INS + k0 + kkL];
        wss[kkL][rL + 16] = W[(cbase + rL + 16) * INS + k0 + kkL];
        wss[kkL][rL + 32] = W[(cbase + rL + 32) * INS + k0 + kkL];
        wss[kkL][rL + 48] = W[(cbase + rL + 48) * INS + k0 + kkL];
        __syncthreads();

        #pragma unroll
        for (int kk = 0; kk < 16; ++kk) {
            float2 a = *(const float2*)&xs[kk][ty * 2];
            float4 w = *(const float4*)&wss[kk][tx * 4];
            acc[0][0] += a.x * w.x;  acc[0][1] += a.x * w.y;
            acc[0][2] += a.x * w.z;  acc[0][3] += a.x * w.w;
            acc[1][0] += a.y * w.x;  acc[1][1] += a.y * w.y;
            acc[1][2] += a.y * w.z;  acc[1][3] += a.y * w.w;
        }
        __syncthreads();
    }

    const float LOG2E = 1.4426950408889634f;
    const int c = cbase + tx * 4;
    float4 bq = *(const float4*)&bias[c];
    const int k = c >> 4;
    const int d = c & 15;
    #pragma unroll
    for (int ii = 0; ii < 2; ++ii) {
        const int i = ibase + ty * 2 + ii;
        float4 v;
        v.x = (acc[ii][0] + bq.x) * LOG2E;
        v.y = (acc[ii][1] + bq.y) * LOG2E;
        v.z = (acc[ii][2] + bq.z) * LOG2E;
        v.w = (acc[ii][3] + bq.w) * LOG2E;
        *(float4*)&featT[(k * NPTS + i) * DDIM + d] = v;
    }
}

// ---------------- Kernel B: o_b[i,k] = sum_j exp2(-sum_d |f[i,k,d]-f[j,k,d]|) - 1
// grid (KDIM=64, NPTS/64=8), 256 thr (4 waves). Wave w sweeps j in [w*128, w*128+128),
// j is wave-uniform -> broadcast LDS reads.
__global__ __launch_bounds__(256) void pairwise_kernel(
    const float* __restrict__ featT,  // [64][512][16], pre-scaled by log2e
    float* __restrict__ out)          // [512][576]
{
    const int k = blockIdx.x;
    const int ibase = blockIdx.y * 64;

    __shared__ float fj[NPTS * DDIM];  // 32 KB: full k-slice
    __shared__ float part[4][64];

    // cooperative fill: 2048 float4 / 256 threads = 8 each, coalesced
    {
        const float4* src = (const float4*)(featT + (size_t)k * NPTS * DDIM);
        float4* dst = (float4*)fj;
        #pragma unroll
        for (int t = 0; t < 8; ++t)
            dst[threadIdx.x + t * 256] = src[threadIdx.x + t * 256];
    }

    const int lane = threadIdx.x & 63;
    const int wv   = threadIdx.x >> 6;
    const int i    = ibase + lane;

    float fi[16];
    {
        const float4* p = (const float4*)(featT + ((size_t)k * NPTS + i) * DDIM);
        float4 v0 = p[0], v1 = p[1], v2 = p[2], v3 = p[3];
        fi[0]=v0.x; fi[1]=v0.y; fi[2]=v0.z; fi[3]=v0.w;
        fi[4]=v1.x; fi[5]=v1.y; fi[6]=v1.z; fi[7]=v1.w;
        fi[8]=v2.x; fi[9]=v2.y; fi[10]=v2.z; fi[11]=v2.w;
        fi[12]=v3.x; fi[13]=v3.y; fi[14]=v3.z; fi[15]=v3.w;
    }
    __syncthreads();

    float acc0 = 0.f, acc1 = 0.f;
    const float* fp = fj + wv * 128 * DDIM;
    #pragma unroll 1
    for (int jj = 0; jj < 128; jj += 2) {
        // j even
        {
            float n0=0.f, n1=0.f, n2=0.f, n3=0.f;
            #pragma unroll
            for (int d = 0; d < 4; ++d) {
                n0 += fabsf(fi[d]      - fp[d]);
                n1 += fabsf(fi[d + 4]  - fp[d + 4]);
                n2 += fabsf(fi[d + 8]  - fp[d + 8]);
                n3 += fabsf(fi[d + 12] - fp[d + 12]);
            }
            acc0 += exp2_fast(-((n0 + n1) + (n2 + n3)));
        }
        // j odd
        {
            float n0=0.f, n1=0.f, n2=0.f, n3=0.f;
            #pragma unroll
            for (int d = 0; d < 4; ++d) {
                n0 += fabsf(fi[d]      - fp[DDIM + d]);
                n1 += fabsf(fi[d + 4]  - fp[DDIM + d + 4]);
                n2 += fabsf(fi[d + 8]  - fp[DDIM + d + 8]);
                n3 += fabsf(fi[d + 12] - fp[DDIM + d + 12]);
            }
            acc1 += exp2_fast(-((n0 + n1) + (n2 + n3)));
        }
        fp += 2 * DDIM;
    }

    part[wv][lane] = acc0 + acc1;
    __syncthreads();

    if (wv == 0) {
        // diagonal j==i contributed exactly exp2(-0)=1 (identical bits); ref has exp(-1e6)=0
        float o = ((part[0][lane] + part[1][lane]) + (part[2][lane] + part[3][lane])) - 1.0f;
        out[(size_t)i * OUTC + INS + k] = o;
    }
}

// ---------------- Kernel C: copy x into out[:, 0:512] (float4, row stride 576/4=144)
__global__ __launch_bounds__(256) void copy_x_kernel(
    const float* __restrict__ x, float* __restrict__ out)
{
    const int idx = blockIdx.x * 256 + threadIdx.x;  // 512*128 = 65536 float4
    const int i  = idx >> 7;
    const int j4 = idx & 127;
    ((float4*)out)[i * (OUTC / 4) + j4] = ((const float4*)x)[idx];
}

extern "C" void kernel_launch(void* const* d_in, const int* in_sizes, int n_in,
                              void* d_out, int out_size, void* d_ws, size_t ws_size,
                              hipStream_t stream) {
    const float* x    = (const float*)d_in[0];
    const float* W    = (const float*)d_in[1];
    const float* bias = (const float*)d_in[2];
    float* out = (float*)d_out;
    float* featT = (float*)d_ws;  // 64*512*16*4 = 2 MB

    gemm_kernel<<<dim3(CDIM / 64, NPTS / 32), 256, 0, stream>>>(x, W, bias, featT);
    copy_x_kernel<<<dim3(NPTS * (INS / 4) / 256), 256, 0, stream>>>(x, out);
    pairwise_kernel<<<dim3(KDIM, NPTS / 64), 256, 0, stream>>>(featT, out);
}

// Round 2
// 97.677 us; speedup vs baseline: 1.0875x; 1.0875x over previous
//
#include <hip/hip_runtime.h>

#define NPTS 512      // N rows
#define INS  512      // INSIZE
#define KDIM 64       // K groups
#define DDIM 16       // D per group
#define CDIM (KDIM*DDIM)  // 1024 output cols of the linear
#define OUTC (INS + KDIM) // 576
#define KSPLIT 4
#define FEAT_ELEMS ((size_t)NPTS * CDIM)  // 524288 floats per split buffer

__device__ __forceinline__ float exp2_fast(float x) {
    return __builtin_amdgcn_exp2f(x);
}

// ---------------- Kernel A: partial feat = (x @ W^T [+ b]) * log2(e) over K-range,
// stored as featT[ks][k][i][d]. tile: 32 i x 64 c, k-step 16.
// grid (16 ctile, 16 itile, 4 ksplit) = 1024 blocks -> 4 waves/SIMD.
__global__ __launch_bounds__(256) void gemm_kernel(
    const float* __restrict__ x,    // [512][512]
    const float* __restrict__ W,    // [1024][512]
    const float* __restrict__ bias, // [1024]
    float* __restrict__ featT)      // KSPLIT x [64][512][16]
{
    const int tid = threadIdx.x;
    const int cbase = blockIdx.x * 64;
    const int ibase = blockIdx.y * 32;
    const int kbase = blockIdx.z * (INS / KSPLIT);  // 128-wide K-range

    __shared__ float xs[16][32 + 2];   // [kk][i]
    __shared__ float wss[16][64 + 4];  // [kk][c]

    const int tx = tid & 15;   // c group: tx*4 .. +3
    const int ty = tid >> 4;   // i group: ty*2 .. +1

    float acc[2][4] = {};

    const int kkL = tid & 15;
    const int rL  = tid >> 4;  // 0..15

    for (int k0 = kbase; k0 < kbase + INS / KSPLIT; k0 += 16) {
        xs[kkL][rL]      = x[(ibase + rL) * INS + k0 + kkL];
        xs[kkL][rL + 16] = x[(ibase + rL + 16) * INS + k0 + kkL];
        wss[kkL][rL]      = W[(cbase + rL) * INS + k0 + kkL];
        wss[kkL][rL + 16] = W[(cbase + rL + 16) * INS + k0 + kkL];
        wss[kkL][rL + 32] = W[(cbase + rL + 32) * INS + k0 + kkL];
        wss[kkL][rL + 48] = W[(cbase + rL + 48) * INS + k0 + kkL];
        __syncthreads();

        #pragma unroll
        for (int kk = 0; kk < 16; ++kk) {
            float2 a = *(const float2*)&xs[kk][ty * 2];
            float4 w = *(const float4*)&wss[kk][tx * 4];
            acc[0][0] += a.x * w.x;  acc[0][1] += a.x * w.y;
            acc[0][2] += a.x * w.z;  acc[0][3] += a.x * w.w;
            acc[1][0] += a.y * w.x;  acc[1][1] += a.y * w.y;
            acc[1][2] += a.y * w.z;  acc[1][3] += a.y * w.w;
        }
        __syncthreads();
    }

    const float LOG2E = 1.4426950408889634f;
    const float bsel = (blockIdx.z == 0) ? 1.0f : 0.0f;  // bias only in split 0
    const int c = cbase + tx * 4;
    float4 bq = *(const float4*)&bias[c];
    const int k = c >> 4;
    const int d = c & 15;
    float* dst = featT + (size_t)blockIdx.z * FEAT_ELEMS;
    #pragma unroll
    for (int ii = 0; ii < 2; ++ii) {
        const int i = ibase + ty * 2 + ii;
        float4 v;
        v.x = (acc[ii][0] + bq.x * bsel) * LOG2E;
        v.y = (acc[ii][1] + bq.y * bsel) * LOG2E;
        v.z = (acc[ii][2] + bq.z * bsel) * LOG2E;
        v.w = (acc[ii][3] + bq.w * bsel) * LOG2E;
        *(float4*)&dst[((size_t)k * NPTS + i) * DDIM + d] = v;
    }
}

// ---------------- Kernel B: out[:, :512] = x ; out[:, 512:576] = -1.0
// (the -1 absorbs the diagonal's exp2(-0)=1; pairwise atomically accumulates on top)
__global__ __launch_bounds__(256) void init_out_kernel(
    const float* __restrict__ x, float* __restrict__ out)
{
    const int idx = blockIdx.x * 256 + threadIdx.x;  // 512 * 144 = 73728 float4
    const int i  = idx / (OUTC / 4);   // /144 -> compiler magic-mul
    const int j4 = idx - i * (OUTC / 4);
    float4 v;
    if (j4 < INS / 4) {
        v = ((const float4*)x)[i * (INS / 4) + j4];
    } else {
        v = make_float4(-1.0f, -1.0f, -1.0f, -1.0f);
    }
    ((float4*)out)[idx] = v;
}

// sum of the 4 split buffers at float offset `off` -> fi[16]
// NOTE: summation order must match the fj staging exactly (bitwise) so the
// diagonal pair gives diff == 0 exactly.
__device__ __forceinline__ void load_feat16(
    const float* f0, const float* f1, const float* f2, const float* f3,
    size_t off, float* fi)
{
    #pragma unroll
    for (int q = 0; q < 4; ++q) {
        float4 a = *(const float4*)(f0 + off + q * 4);
        float4 b = *(const float4*)(f1 + off + q * 4);
        float4 c = *(const float4*)(f2 + off + q * 4);
        float4 d = *(const float4*)(f3 + off + q * 4);
        fi[q * 4 + 0] = (a.x + b.x) + (c.x + d.x);
        fi[q * 4 + 1] = (a.y + b.y) + (c.y + d.y);
        fi[q * 4 + 2] = (a.z + b.z) + (c.z + d.z);
        fi[q * 4 + 3] = (a.w + b.w) + (c.w + d.w);
    }
}

// ---------------- Kernel C: o_b accumulation.
// grid (64 k, 4 itile(128 i), 4 jq(128 j)) = 1024 blocks x 256 thr = 4 waves/SIMD.
// lane owns i0 = itile*128+lane and i1 = i0+64; wave wv sweeps 32 j's.
__global__ __launch_bounds__(256, 4) void pairwise_kernel(
    const float* __restrict__ f0, const float* __restrict__ f1,
    const float* __restrict__ f2, const float* __restrict__ f3,
    float* __restrict__ out)          // [512][576]
{
    const int k     = blockIdx.x;
    const int itile = blockIdx.y;
    const int jq    = blockIdx.z;

    __shared__ float fj[128 * DDIM];   // 8 KB: this block's j-slice (summed splits)
    __shared__ float part[4][128];

    // stage j-range [jq*128, +128): 512 float4, 2 per thread
    {
        const size_t base = ((size_t)k * NPTS + jq * 128) * DDIM;
        const float4* s0 = (const float4*)(f0 + base);
        const float4* s1 = (const float4*)(f1 + base);
        const float4* s2 = (const float4*)(f2 + base);
        const float4* s3 = (const float4*)(f3 + base);
        float4* dst = (float4*)fj;
        #pragma unroll
        for (int u = 0; u < 2; ++u) {
            int idx = threadIdx.x + u * 256;
            float4 a = s0[idx], b = s1[idx], c = s2[idx], d = s3[idx];
            float4 r;
            r.x = (a.x + b.x) + (c.x + d.x);
            r.y = (a.y + b.y) + (c.y + d.y);
            r.z = (a.z + b.z) + (c.z + d.z);
            r.w = (a.w + b.w) + (c.w + d.w);
            dst[idx] = r;
        }
    }

    const int lane = threadIdx.x & 63;
    const int wv   = threadIdx.x >> 6;
    const int i0   = itile * 128 + lane;
    const int i1   = i0 + 64;

    float fi0[16], fi1[16];
    load_feat16(f0, f1, f2, f3, ((size_t)k * NPTS + i0) * DDIM, fi0);
    load_feat16(f0, f1, f2, f3, ((size_t)k * NPTS + i1) * DDIM, fi1);
    __syncthreads();

    float acc0 = 0.f, acc1 = 0.f;
    const float* fp = fj + wv * 32 * DDIM;
    #pragma unroll 2
    for (int jj = 0; jj < 32; ++jj) {
        const float* p = fp + jj * DDIM;
        float4 q0 = *(const float4*)(p);
        float4 q1 = *(const float4*)(p + 4);
        float4 q2 = *(const float4*)(p + 8);
        float4 q3 = *(const float4*)(p + 12);
        // i0
        {
            float a0 = fabsf(fi0[0]  - q0.x) + fabsf(fi0[1]  - q0.y)
                     + fabsf(fi0[2]  - q0.z) + fabsf(fi0[3]  - q0.w);
            float a1 = fabsf(fi0[4]  - q1.x) + fabsf(fi0[5]  - q1.y)
                     + fabsf(fi0[6]  - q1.z) + fabsf(fi0[7]  - q1.w);
            float a2 = fabsf(fi0[8]  - q2.x) + fabsf(fi0[9]  - q2.y)
                     + fabsf(fi0[10] - q2.z) + fabsf(fi0[11] - q2.w);
            float a3 = fabsf(fi0[12] - q3.x) + fabsf(fi0[13] - q3.y)
                     + fabsf(fi0[14] - q3.z) + fabsf(fi0[15] - q3.w);
            acc0 += exp2_fast(-((a0 + a1) + (a2 + a3)));
        }
        // i1
        {
            float b0 = fabsf(fi1[0]  - q0.x) + fabsf(fi1[1]  - q0.y)
                     + fabsf(fi1[2]  - q0.z) + fabsf(fi1[3]  - q0.w);
            float b1 = fabsf(fi1[4]  - q1.x) + fabsf(fi1[5]  - q1.y)
                     + fabsf(fi1[6]  - q1.z) + fabsf(fi1[7]  - q1.w);
            float b2 = fabsf(fi1[8]  - q2.x) + fabsf(fi1[9]  - q2.y)
                     + fabsf(fi1[10] - q2.z) + fabsf(fi1[11] - q2.w);
            float b3 = fabsf(fi1[12] - q3.x) + fabsf(fi1[13] - q3.y)
                     + fabsf(fi1[14] - q3.z) + fabsf(fi1[15] - q3.w);
            acc1 += exp2_fast(-((b0 + b1) + (b2 + b3)));
        }
    }

    part[wv][lane]      = acc0;
    part[wv][lane + 64] = acc1;
    __syncthreads();

    if (threadIdx.x < 128) {
        float s = (part[0][threadIdx.x] + part[1][threadIdx.x])
                + (part[2][threadIdx.x] + part[3][threadIdx.x]);
        const int i = itile * 128 + threadIdx.x;
        atomicAdd(&out[(size_t)i * OUTC + INS + k], s);
    }
}

extern "C" void kernel_launch(void* const* d_in, const int* in_sizes, int n_in,
                              void* d_out, int out_size, void* d_ws, size_t ws_size,
                              hipStream_t stream) {
    const float* x    = (const float*)d_in[0];
    const float* W    = (const float*)d_in[1];
    const float* bias = (const float*)d_in[2];
    float* out = (float*)d_out;
    float* featT = (float*)d_ws;  // 4 x 2 MB split buffers

    gemm_kernel<<<dim3(CDIM / 64, NPTS / 32, KSPLIT), 256, 0, stream>>>(x, W, bias, featT);
    init_out_kernel<<<dim3(NPTS * (OUTC / 4) / 256), 256, 0, stream>>>(x, out);
    pairwise_kernel<<<dim3(KDIM, 4, 4), 256, 0, stream>>>(
        featT, featT + FEAT_ELEMS, featT + 2 * FEAT_ELEMS, featT + 3 * FEAT_ELEMS, out);
}